// Round 13
// baseline (383.495 us; speedup 1.0000x reference)
//
#include <hip/hip_runtime.h>
#include <stdint.h>

// Calibration-histogram kernel for MI355X (round 13).
// probs: (1,2,4096,4096) f32, labels: (1,1,4096,4096) i32.
// Outputs (flat, 90 f32): count0[15], csum0[15], asum0[15], count1[15], csum1[15], asum1[15].
//
// Round-12 post-mortem: acc[] array went to SCRATCH (VGPR_Count=44 proves
// the 32 accumulators were not register-resident; _Pragma unroll inside the
// macro failed -> runtime-indexed array, rule #20). Scratch RMW at L2
// latency = same serial chain as the LDS variants -> 165 us, 30% VALU duty.
// Fix: 30 NAMED SCALAR accumulators (a0..a14, b0..b14) + fully explicit
// 15-way select-adds -> guaranteed VGPRs. Packed u32 per bin:
//   [31:14] csum (fixed-point, conf*2048 truncated) | [13:7] asum | [6:0] count
// 1536 blocks x 256 thr -> <=11 iters/thread -> count<=44; after one
// shfl_xor(32) pair-reduce <=88 < 128; csum <= 88*2048 = 180224 < 2^18. Safe.
// Epilogue: pair-reduce in regs, lanes<32 write hist[30][128] (15 KB LDS),
// bank-rotated merge + 8-lane shfl + 90 global float atomics per block.

#define NBINS 15

__global__ void zero_out_kernel(float* out, int n) {
    int i = blockIdx.x * blockDim.x + threadIdx.x;
    if (i < n) out[i] = 0.0f;
}

// Compute packed update value v and bin (0..14) for one element.
// bin = min(int(c*15), 14); invalid (c<=0) -> v=0 (bin harmless, adds 0).
#define PACK(c_, m_)                                                  \
    {                                                                 \
        float _c = (c_);                                              \
        bin = (int)fminf(_c * 15.0f, 14.0f);                          \
        unsigned _cf = (unsigned)(_c * 2048.0f);                      \
        v = (_cf << 14) | ((m_) ? 0x80u : 0u) | 1u;                   \
        v = (_c > 0.0f) ? v : 0u;                                     \
    }

// 15 explicit select-adds into NAMED scalars A##0..A##14 (compile-time only).
#define SELS(A)                                                                    \
    A##0  += (bin == 0 ) ? v : 0u;  A##1  += (bin == 1 ) ? v : 0u;                 \
    A##2  += (bin == 2 ) ? v : 0u;  A##3  += (bin == 3 ) ? v : 0u;                 \
    A##4  += (bin == 4 ) ? v : 0u;  A##5  += (bin == 5 ) ? v : 0u;                 \
    A##6  += (bin == 6 ) ? v : 0u;  A##7  += (bin == 7 ) ? v : 0u;                 \
    A##8  += (bin == 8 ) ? v : 0u;  A##9  += (bin == 9 ) ? v : 0u;                 \
    A##10 += (bin == 10) ? v : 0u;  A##11 += (bin == 11) ? v : 0u;                 \
    A##12 += (bin == 12) ? v : 0u;  A##13 += (bin == 13) ? v : 0u;                 \
    A##14 += (bin == 14) ? v : 0u;

#define PAIR_REDUCE(x) x += (unsigned)__shfl_xor((int)(x), 32);

__global__ __launch_bounds__(256, 6) void calib_hist_kernel(
        const float* __restrict__ probs, const int* __restrict__ labels,
        float* __restrict__ out, int npix) {
    unsigned a0=0,a1=0,a2=0,a3=0,a4=0,a5=0,a6=0,a7=0,a8=0,a9=0,a10=0,a11=0,a12=0,a13=0,a14=0;
    unsigned b0=0,b1=0,b2=0,b3=0,b4=0,b5=0,b6=0,b7=0,b8=0,b9=0,b10=0,b11=0,b12=0,b13=0,b14=0;

    const float4* p0 = (const float4*)probs;           // channel 0
    const float4* p1 = (const float4*)(probs + npix);  // channel 1
    const int4*   lb = (const int4*)labels;
    int nvec   = npix >> 2;
    int stride = gridDim.x * blockDim.x;
    int tid    = threadIdx.x;

    for (int i = blockIdx.x * blockDim.x + tid; i < nvec; i += stride) {
        float4 a = p0[i];
        float4 b = p1[i];
        int4   l = lb[i];
        unsigned v; int bin;
        PACK(a.x, l.x == 0) SELS(a)
        PACK(b.x, l.x == 1) SELS(b)
        PACK(a.y, l.y == 0) SELS(a)
        PACK(b.y, l.y == 1) SELS(b)
        PACK(a.z, l.z == 0) SELS(a)
        PACK(b.z, l.z == 1) SELS(b)
        PACK(a.w, l.w == 0) SELS(a)
        PACK(b.w, l.w == 1) SELS(b)
    }

    // Pair-reduce lane ^ 32 in registers (count<=44 -> <=88 < 128: no carry).
    PAIR_REDUCE(a0) PAIR_REDUCE(a1) PAIR_REDUCE(a2) PAIR_REDUCE(a3) PAIR_REDUCE(a4)
    PAIR_REDUCE(a5) PAIR_REDUCE(a6) PAIR_REDUCE(a7) PAIR_REDUCE(a8) PAIR_REDUCE(a9)
    PAIR_REDUCE(a10) PAIR_REDUCE(a11) PAIR_REDUCE(a12) PAIR_REDUCE(a13) PAIR_REDUCE(a14)
    PAIR_REDUCE(b0) PAIR_REDUCE(b1) PAIR_REDUCE(b2) PAIR_REDUCE(b3) PAIR_REDUCE(b4)
    PAIR_REDUCE(b5) PAIR_REDUCE(b6) PAIR_REDUCE(b7) PAIR_REDUCE(b8) PAIR_REDUCE(b9)
    PAIR_REDUCE(b10) PAIR_REDUCE(b11) PAIR_REDUCE(b12) PAIR_REDUCE(b13) PAIR_REDUCE(b14)

    // Lanes <32 of each wave write hist[e][col], col = wid*32+lane (0..127).
    // bank(word = e*128+col) = col&31 = lane -> conflict-free stores.
    __shared__ unsigned hist[30 * 128];   // 15 KB
    int lane = tid & 63, wid = tid >> 6;
    if (lane < 32) {
        int col = wid * 32 + lane;
        hist[ 0*128+col]=a0;  hist[ 1*128+col]=a1;  hist[ 2*128+col]=a2;
        hist[ 3*128+col]=a3;  hist[ 4*128+col]=a4;  hist[ 5*128+col]=a5;
        hist[ 6*128+col]=a6;  hist[ 7*128+col]=a7;  hist[ 8*128+col]=a8;
        hist[ 9*128+col]=a9;  hist[10*128+col]=a10; hist[11*128+col]=a11;
        hist[12*128+col]=a12; hist[13*128+col]=a13; hist[14*128+col]=a14;
        hist[15*128+col]=b0;  hist[16*128+col]=b1;  hist[17*128+col]=b2;
        hist[18*128+col]=b3;  hist[19*128+col]=b4;  hist[20*128+col]=b5;
        hist[21*128+col]=b6;  hist[22*128+col]=b7;  hist[23*128+col]=b8;
        hist[24*128+col]=b9;  hist[25*128+col]=b10; hist[26*128+col]=b11;
        hist[27*128+col]=b12; hist[28*128+col]=b13; hist[29*128+col]=b14;
    }
    __syncthreads();

    // Merge: thread h<240 owns entry e=h>>3, 16-col chunk (h&7)*16 rotated by
    // h. Unpack BEFORE summing (packed fields would overflow). Then 8-lane
    // shfl_xor reduce and one atomic triple per entry.
    if (tid < 240) {
        int e = tid >> 3;                  // 0..29
        unsigned cnt = 0, asum = 0, csum = 0;
        int chunk = (tid & 7) * 16;
        #pragma unroll
        for (int j = 0; j < 16; ++j) {
            int col = chunk + ((j + tid) & 15);
            unsigned x = hist[e * 128 + col];
            cnt  += x & 0x7Fu;
            asum += (x >> 7) & 0x7Fu;
            csum += x >> 14;
        }
        cnt  += __shfl_xor(cnt, 1); asum += __shfl_xor(asum, 1); csum += __shfl_xor(csum, 1);
        cnt  += __shfl_xor(cnt, 2); asum += __shfl_xor(asum, 2); csum += __shfl_xor(csum, 2);
        cnt  += __shfl_xor(cnt, 4); asum += __shfl_xor(asum, 4); csum += __shfl_xor(csum, 4);
        if ((tid & 7) == 0) {
            int ch  = (e >= 15) ? 1 : 0;
            int bin = e - ch * 15;
            float* obase = out + ch * 45;
            atomicAdd(obase + bin,             (float)cnt);
            atomicAdd(obase + NBINS + bin,     (float)csum * (1.0f / 2048.0f));
            atomicAdd(obase + 2 * NBINS + bin, (float)asum);
        }
    }
}

extern "C" void kernel_launch(void* const* d_in, const int* in_sizes, int n_in,
                              void* d_out, int out_size, void* d_ws, size_t ws_size,
                              hipStream_t stream) {
    const float* probs  = (const float*)d_in[0];
    const int*   labels = (const int*)d_in[1];
    float*       out    = (float*)d_out;
    int npix = in_sizes[1];  // 4096*4096 pixels; probs has 2*npix elements

    zero_out_kernel<<<(out_size + 127) / 128, 128, 0, stream>>>(out, out_size);

    // 1536 blocks = 6 blocks/CU (launch_bounds(256,6): VGPR cap ~85,
    // 24 waves/CU). <=11 iters/thread keeps packed fields carry-safe.
    calib_hist_kernel<<<1536, 256, 0, stream>>>(probs, labels, out, npix);
}

// Round 14
// 311.059 us; speedup vs baseline: 1.2329x; 1.2329x over previous
//
#include <hip/hip_runtime.h>
#include <stdint.h>

// Calibration-histogram kernel for MI355X (round 14).
// probs: (1,2,4096,4096) f32, labels: (1,1,4096,4096) i32.
// Outputs (flat, 90 f32): count0[15], csum0[15], asum0[15], count1[15], csum1[15], asum1[15].
//
// Round-13 post-mortem: 30 named scalars STILL spilled (VGPR_Count=40,
// WRITE_SIZE exploded to 156 MB = scratch RMW traffic). Evidence across
// rounds: any __launch_bounds__ 2nd arg -> VGPR collapse 40-44 + spill;
// r7 without it -> VGPR 88, no scratch. Fixes:
//   1. NO second launch_bounds arg.
//   2. CHANNEL-SPLIT blocks: each block accumulates ONE channel -> only
//      15 named u32 accumulators + 2 vec4 loads live (~35 VGPR demand).
//      ch=(bid>>3)&1 so a ch0/ch1 pair reading the same labels region sits
//      on the same XCD (consecutive round-robin) -> labels 2nd read L2-hits.
// Packed u32 per bin: [31:14] csum (conf*2048 trunc) | [13:7] asum | [6:0] count.
// 3072 blocks (1536/channel) x 256 thr -> <=11 iters -> count<=44; after
// shfl_xor(32) pair-reduce <=88 < 128; csum <= 88*2048 = 180224 < 2^18. Safe.

#define NBINS 15

__global__ void zero_out_kernel(float* out, int n) {
    int i = blockIdx.x * blockDim.x + threadIdx.x;
    if (i < n) out[i] = 0.0f;
}

// v/bin for one element. m = label ^ flip gives (label==ch) since label in {0,1}.
#define PACK(c_, lab_)                                                \
    {                                                                 \
        float _c = (c_);                                              \
        bin = (int)fminf(_c * 15.0f, 14.0f);                          \
        unsigned _cf = (unsigned)(_c * 2048.0f);                      \
        v = (_cf << 14) | ((unsigned)(((lab_) ^ flip) & 1) << 7) | 1u;\
        v = (_c > 0.0f) ? v : 0u;                                     \
    }

#define SEL_ALL                                                       \
    s0  += (bin == 0 ) ? v : 0u;  s1  += (bin == 1 ) ? v : 0u;        \
    s2  += (bin == 2 ) ? v : 0u;  s3  += (bin == 3 ) ? v : 0u;        \
    s4  += (bin == 4 ) ? v : 0u;  s5  += (bin == 5 ) ? v : 0u;        \
    s6  += (bin == 6 ) ? v : 0u;  s7  += (bin == 7 ) ? v : 0u;        \
    s8  += (bin == 8 ) ? v : 0u;  s9  += (bin == 9 ) ? v : 0u;        \
    s10 += (bin == 10) ? v : 0u;  s11 += (bin == 11) ? v : 0u;        \
    s12 += (bin == 12) ? v : 0u;  s13 += (bin == 13) ? v : 0u;        \
    s14 += (bin == 14) ? v : 0u;

#define PR(x) x += (unsigned)__shfl_xor((int)(x), 32);

__global__ __launch_bounds__(256) void calib_hist_kernel(
        const float* __restrict__ probs, const int* __restrict__ labels,
        float* __restrict__ out, int npix) {
    // Block -> (channel, pair index). Pairs (same p, ch0/ch1) are 8 apart in
    // blockIdx -> same XCD slot under round-robin -> shared labels L2 locality.
    int g  = blockIdx.x;
    int ch = (g >> 3) & 1;
    int p  = ((g >> 4) << 3) | (g & 7);          // 0 .. gridDim/2 - 1
    unsigned flip = (unsigned)(ch ^ 1);

    unsigned s0=0,s1=0,s2=0,s3=0,s4=0,s5=0,s6=0,s7=0,s8=0,s9=0,s10=0,s11=0,s12=0,s13=0,s14=0;

    const float4* pc = (const float4*)(probs + (size_t)ch * npix);
    const int4*   lb = (const int4*)labels;
    int nvec    = npix >> 2;
    int nblkch  = gridDim.x >> 1;                // blocks per channel
    int stride  = nblkch * 256;
    int tid     = threadIdx.x;

    for (int i = p * 256 + tid; i < nvec; i += stride) {
        float4 a = pc[i];
        int4   l = lb[i];
        unsigned v; int bin;
        PACK(a.x, l.x) SEL_ALL
        PACK(a.y, l.y) SEL_ALL
        PACK(a.z, l.z) SEL_ALL
        PACK(a.w, l.w) SEL_ALL
    }

    // Pair-reduce lane^32 in registers (count<=44 -> <=88 < 128: no carry).
    PR(s0) PR(s1) PR(s2) PR(s3) PR(s4) PR(s5) PR(s6) PR(s7)
    PR(s8) PR(s9) PR(s10) PR(s11) PR(s12) PR(s13) PR(s14)

    // Lanes <32 of each of 4 waves write hist[e][col], col = wid*32+lane.
    // bank(word = e*128+col) = col&31 = lane -> conflict-free stores.
    __shared__ unsigned hist[15 * 128];   // 7.5 KB
    int lane = tid & 63, wid = tid >> 6;
    if (lane < 32) {
        int col = wid * 32 + lane;
        hist[ 0*128+col]=s0;  hist[ 1*128+col]=s1;  hist[ 2*128+col]=s2;
        hist[ 3*128+col]=s3;  hist[ 4*128+col]=s4;  hist[ 5*128+col]=s5;
        hist[ 6*128+col]=s6;  hist[ 7*128+col]=s7;  hist[ 8*128+col]=s8;
        hist[ 9*128+col]=s9;  hist[10*128+col]=s10; hist[11*128+col]=s11;
        hist[12*128+col]=s12; hist[13*128+col]=s13; hist[14*128+col]=s14;
    }
    __syncthreads();

    // Merge: thread h<120 owns bin e=h>>3 and 16-col chunk (h&7)*16, rotated
    // by h. Unpack BEFORE summing. 8-lane shfl reduce, one atomic triple/bin.
    if (tid < 120) {
        int e = tid >> 3;                  // 0..14
        unsigned cnt = 0, asum = 0, csum = 0;
        int chunk = (tid & 7) * 16;
        #pragma unroll
        for (int j = 0; j < 16; ++j) {
            int col = chunk + ((j + tid) & 15);
            unsigned x = hist[e * 128 + col];
            cnt  += x & 0x7Fu;
            asum += (x >> 7) & 0x7Fu;
            csum += x >> 14;
        }
        cnt  += __shfl_xor(cnt, 1); asum += __shfl_xor(asum, 1); csum += __shfl_xor(csum, 1);
        cnt  += __shfl_xor(cnt, 2); asum += __shfl_xor(asum, 2); csum += __shfl_xor(csum, 2);
        cnt  += __shfl_xor(cnt, 4); asum += __shfl_xor(asum, 4); csum += __shfl_xor(csum, 4);
        if ((tid & 7) == 0) {
            float* obase = out + ch * 45;
            atomicAdd(obase + e,             (float)cnt);
            atomicAdd(obase + NBINS + e,     (float)csum * (1.0f / 2048.0f));
            atomicAdd(obase + 2 * NBINS + e, (float)asum);
        }
    }
}

extern "C" void kernel_launch(void* const* d_in, const int* in_sizes, int n_in,
                              void* d_out, int out_size, void* d_ws, size_t ws_size,
                              hipStream_t stream) {
    const float* probs  = (const float*)d_in[0];
    const int*   labels = (const int*)d_in[1];
    float*       out    = (float*)d_out;
    int npix = in_sizes[1];  // 4096*4096 pixels; probs has 2*npix elements

    zero_out_kernel<<<(out_size + 127) / 128, 128, 0, stream>>>(out, out_size);

    // 3072 blocks = 1536 per channel; <=11 iters/thread (carry-safe).
    calib_hist_kernel<<<3072, 256, 0, stream>>>(probs, labels, out, npix);
}